// Round 12
// baseline (362.004 us; speedup 1.0000x reference)
//
#include <hip/hip_runtime.h>
#include <math.h>

#define PI_F   3.14159265358979f
#define QF     0.88249690258459546f   /* exp(-1/8) */
#define INV255 (1.0f/255.0f)

__device__ __forceinline__ float softplus_f(float x){
    return fmaxf(x, 0.0f) + __logf(1.0f + __expf(-fabsf(x)));
}
__device__ __forceinline__ float tanh_fast(float x){
    const float e = __expf(2.0f*x);
    return fmaf(-2.0f, __builtin_amdgcn_rcpf(e + 1.0f), 1.0f);
}

/* ---- lane exchanges (all HW-verified equivalent R1==R2; row_ror:8 verified R11) ---- */
template<int CTRL>
__device__ __forceinline__ float dppmov(float x){
    return __int_as_float(__builtin_amdgcn_mov_dpp(__float_as_int(x), CTRL, 0xF, 0xF, false));
}
__device__ __forceinline__ float lxor1 (float x){ return dppmov<0xB1>(x);  }  /* quad_perm(1,0,3,2) */
__device__ __forceinline__ float lxor2 (float x){ return dppmov<0x4E>(x);  }  /* quad_perm(2,3,0,1) */
__device__ __forceinline__ float lxor8 (float x){ return dppmov<0x128>(x); }  /* row_ror:8 == i^8   */
__device__ __forceinline__ float lxor4 (float x){ return __int_as_float(__builtin_amdgcn_ds_swizzle(__float_as_int(x), 0x101F)); }
__device__ __forceinline__ float lxor16(float x){ return __int_as_float(__builtin_amdgcn_ds_swizzle(__float_as_int(x), 0x401F)); }
__device__ __forceinline__ float lxor32(float x){ return __shfl_xor(x, 32, 64); }

template<int CTRL>
__device__ __forceinline__ float dppadd(float v){
    return v + __int_as_float(__builtin_amdgcn_update_dpp(0, __float_as_int(v), CTRL, 0xF, 0xF, true));
}
/* full 64-lane sum, result valid in lane 63 (verified R11) */
__device__ __forceinline__ float wave_sum63(float v){
    v = dppadd<0x111>(v);   /* row_shr:1  */
    v = dppadd<0x112>(v);   /* row_shr:2  */
    v = dppadd<0x114>(v);   /* row_shr:4  */
    v = dppadd<0x118>(v);   /* row_shr:8  */
    v = dppadd<0x142>(v);   /* row_bcast:15 */
    v = dppadd<0x143>(v);   /* row_bcast:31 */
    return v;
}

/* Weighted-Hadamard butterfly, bits 0..5 on lanes, 6..7 on regs. Stages commute. */
__device__ __forceinline__ void bfly20(float (&x)[5][4]){
    const float qv = QF;
    #pragma unroll
    for (int a = 0; a < 5; a++){
        #pragma unroll
        for (int r = 0; r < 4; r++) x[a][r] = fmaf(lxor1 (x[a][r]), qv, x[a][r]);
    }
    #pragma unroll
    for (int a = 0; a < 5; a++){
        #pragma unroll
        for (int r = 0; r < 4; r++) x[a][r] = fmaf(lxor2 (x[a][r]), qv, x[a][r]);
    }
    #pragma unroll
    for (int a = 0; a < 5; a++){
        #pragma unroll
        for (int r = 0; r < 4; r++) x[a][r] = fmaf(lxor8 (x[a][r]), qv, x[a][r]);
    }
    #pragma unroll
    for (int a = 0; a < 5; a++){
        #pragma unroll
        for (int r = 0; r < 4; r++) x[a][r] = fmaf(lxor4 (x[a][r]), qv, x[a][r]);
    }
    #pragma unroll
    for (int a = 0; a < 5; a++){
        #pragma unroll
        for (int r = 0; r < 4; r++) x[a][r] = fmaf(lxor16(x[a][r]), qv, x[a][r]);
    }
    #pragma unroll
    for (int a = 0; a < 5; a++){
        #pragma unroll
        for (int r = 0; r < 4; r++) x[a][r] = fmaf(lxor32(x[a][r]), qv, x[a][r]);
    }
    #pragma unroll
    for (int a = 0; a < 5; a++){
        float t0 = x[a][0], t2 = x[a][2];
        x[a][0] = fmaf(QF, x[a][1], x[a][0]);
        x[a][1] = fmaf(QF, t0,      x[a][1]);
        x[a][2] = fmaf(QF, x[a][3], x[a][2]);
        x[a][3] = fmaf(QF, t2,      x[a][3]);
        t0 = x[a][0]; float t1 = x[a][1];
        x[a][0] = fmaf(QF, x[a][2], x[a][0]);
        x[a][1] = fmaf(QF, x[a][3], x[a][1]);
        x[a][2] = fmaf(QF, t0,      x[a][2]);
        x[a][3] = fmaf(QF, t1,      x[a][3]);
    }
}

/* ---- transpose Ws [256][512] -> WsT [512][256] ---- */
__global__ __launch_bounds__(256) void transpose_ws(
        const float* __restrict__ Ws, float* __restrict__ WsT)
{
    __shared__ float tile[64][65];
    const int rt = blockIdx.x & 3, ct = blockIdx.x >> 2;
    const int r0 = rt*64, c0 = ct*64;
    const int tx = threadIdx.x & 63, ty = threadIdx.x >> 6;
    #pragma unroll
    for (int k = 0; k < 16; k++){
        const int row = ty*16 + k;
        tile[row][tx] = Ws[(r0+row)*512 + c0 + tx];
    }
    __syncthreads();
    #pragma unroll
    for (int k = 0; k < 16; k++){
        const int row = ty*16 + k;
        WsT[(c0+row)*256 + r0 + tx] = tile[tx][row];
    }
}

/* ---------------- fused kernel: one 512-thread block (8 waves) = one batch element; 4 d per wave --------------- */
template<bool USET>
__global__ __launch_bounds__(512) void fused_kernel(
        const float* __restrict__ ns,     /* [B][512] */
        const float* __restrict__ Ws,     /* [256][512] */
        const float* __restrict__ WsT,    /* [512][256] or null */
        const float* __restrict__ bs,     /* [256] */
        const float* __restrict__ WA,     /* [32][32] */
        const float* __restrict__ bA,     /* [32] */
        const float* __restrict__ WP,     /* [32][32] */
        const float* __restrict__ bP,     /* [32] */
        const float* __restrict__ psiA0,  /* [255*32] */
        const float* __restrict__ psiP0,  /* [255*32] */
        const float* __restrict__ Wcomp,  /* [32*255] */
        const float* __restrict__ bcomp,  /* [32] */
        const float* __restrict__ Wread,  /* [64*1024] */
        const float* __restrict__ bread,  /* [64] */
        const float* __restrict__ p_alpha, const float* __restrict__ p_msq,
        const float* __restrict__ p_pw,    const float* __restrict__ p_iw,
        const float* __restrict__ p_evo,   const float* __restrict__ p_pcpl,
        float* __restrict__ out, int Bb)
{
    __shared__ __align__(16) float nsb[512];
    __shared__ __align__(16) float pfe[512];
    __shared__ __align__(16) float fe[256];
    __shared__ __align__(16) float hA[256];
    __shared__ __align__(16) float hP[256];
    __shared__ __align__(16) float red[2][2048];   /* 8 wave-partials, double-buffered */
    __shared__ __align__(16) float ac[1024];
    __shared__ __align__(16) float rop[512];

    const int b   = blockIdx.x;
    const int tid = threadIdx.x;
    const int w   = tid >> 6, l = tid & 63;

    const float alpha = p_alpha[0], msq = p_msq[0], pw = p_pw[0], iw = p_iw[0];
    const float pcpl  = p_pcpl[0];
    const float dt    = 1.0f / (1.0f + __expf(-p_evo[0]));
    const float dta  = dt * alpha * INV255;
    const float dtpw = dt * pw * INV255;
    const float c0   = 1.0f - dt * (msq + iw);
    const float dtiw = dt * iw;

    /* ---- front-end: split-K pairs. f = tid&255, half = tid>>8 ---- */
    nsb[tid] = ns[b*512 + tid];
    __syncthreads();
    {
        const int ff = tid & 255, half = tid >> 8;
        float f = half ? 0.0f : bs[ff];
        const float4* nb4 = (const float4*)nsb + half*64;
        if (USET){
            const float* base = WsT + (half*256)*256 + ff;
            #pragma unroll 8
            for (int j4 = 0; j4 < 64; j4++){
                const float4 nv = nb4[j4];
                const float* col = base + j4*1024;
                f = fmaf(col[0],   nv.x, f);
                f = fmaf(col[256], nv.y, f);
                f = fmaf(col[512], nv.z, f);
                f = fmaf(col[768], nv.w, f);
            }
        } else {
            const float4* wr = (const float4*)(Ws + ff*512) + half*64;
            #pragma unroll 8
            for (int i = 0; i < 64; i++){
                const float4 wv = wr[i], nv = nb4[i];
                f = fmaf(wv.x, nv.x, f); f = fmaf(wv.y, nv.y, f);
                f = fmaf(wv.z, nv.z, f); f = fmaf(wv.w, nv.w, f);
            }
        }
        pfe[tid] = f;
    }
    __syncthreads();
    if (tid < 256) fe[tid] = pfe[tid] + pfe[tid + 256];
    __syncthreads();
    if (tid < 256){   /* fold through W_A / W_phi (linearity of the member-mean) */
        const int s = tid >> 5, d = tid & 31;
        float a = 0.0f, p = 0.0f;
        #pragma unroll 8
        for (int dp = 0; dp < 32; dp++){
            const float fv = fe[s*32 + dp];
            a = fmaf(WA[d*32 + dp], fv, a);
            p = fmaf(WP[d*32 + dp], fv, p);
        }
        hA[tid] = a; hP[tid] = p;
    }
    __syncthreads();

    /* per-thread clique constants: n = l + 64r (cliques replicated per wave; waves differ in d) */
    int   nn[4];
    float krow[4], rdep[4];
    const float m0 = (l == 0) ? 0.0f : 1.0f;
    float c18;
    { const float t1 = 1.0f + QF, t2 = t1*t1, t4 = t2*t2; c18 = t4*t4; } /* (1+q)^8 */
    #pragma unroll
    for (int r = 0; r < 4; r++){
        nn[r] = l + 64*r;
        const int pop = __popc(nn[r]);
        krow[r]  = c18 - __expf(-0.125f * (float)pop);
        rdep[r]  = 1.0f / (float)(pop ? pop : 1);
    }

    /* state + loop-invariant drive terms; d = w*4 + dd (4 d per wave -> 80 persistent floats) */
    float A[4][4], phi[4][4], CAp[4][4], Dsp[4][4], Dcp[4][4];

    #pragma unroll
    for (int dd = 0; dd < 4; dd++){
        const int d = w*4 + dd;
        const float bAd = bA[d], bPd = bP[d];
        float gA_[8], gP_[8];
        #pragma unroll
        for (int s = 0; s < 8; s++){ gA_[s] = hA[s*32 + d]; gP_[s] = hP[s*32 + d]; }
        #pragma unroll
        for (int r = 0; r < 4; r++){
            float sA = 0.0f, sP = 0.0f;
            #pragma unroll
            for (int s = 0; s < 8; s++){
                if ((nn[r] >> s) & 1){ sA += gA_[s]; sP += gP_[s]; }
            }
            const float uA  = fmaf(sA, rdep[r], bAd);
            const float uP  = fmaf(sP, rdep[r], bPd);
            const float Ain = softplus_f(uA);
            const float pin = PI_F * tanh_fast(uP);
            float si, ci; __sincosf(pin, &si, &ci);
            const float ca = dtiw * Ain;
            CAp[dd][r] = ca; Dsp[dd][r] = ca * si; Dcp[dd][r] = ca * ci;
            const int nm1 = (nn[r] > 0) ? (nn[r] - 1) : 0;
            A[dd][r]   = softplus_f(psiA0[nm1*32 + d]);
            phi[dd][r] = psiP0[nm1*32 + d];
        }
    }

    for (int it = 0; it < 5; it++){
        const int pbuf = it & 1;
        float nrm[4] = {0.f, 0.f, 0.f, 0.f};
        #pragma unroll
        for (int dd = 0; dd < 4; dd++){
            float sp[4], cp[4];
            float x[5][4];
            {
                __sincosf(phi[dd][0], &sp[0], &cp[0]);
                const float xa = A[dd][0] * m0;
                x[0][0] = xa;
                x[1][0] = sp[0] * m0;
                x[2][0] = cp[0] * m0;
                x[3][0] = xa * cp[0];
                x[4][0] = xa * sp[0];
            }
            #pragma unroll
            for (int r = 1; r < 4; r++){
                __sincosf(phi[dd][r], &sp[r], &cp[r]);
                const float xa = A[dd][r];
                x[0][r] = xa;
                x[1][r] = sp[r];
                x[2][r] = cp[r];
                x[3][r] = xa * cp[r];
                x[4][r] = xa * sp[r];
            }
            bfly20(x);
            #pragma unroll
            for (int r = 0; r < 4; r++){
                const float Ao   = A[dd][r];
                const float lapp = fmaf(-krow[r], Ao, x[0][r]);
                const float Vp   = fmaf(cp[r], x[3][r], sp[r]*x[4][r]);
                float Aarg = fmaf(c0, Ao, CAp[dd][r]);
                Aarg = fmaf(dta,  lapp, Aarg);
                Aarg = fmaf(dtpw, Vp,   Aarg);
                const float An = softplus_f(Aarg);
                const float Pp = fmaf(-sp[r], x[2][r], cp[r]*x[1][r]);
                const float rr = __builtin_amdgcn_rcpf(An + 1e-8f);
                float pb = fmaf(Dsp[dd][r], cp[r], phi[dd][r]);
                pb = fmaf(-Dcp[dd][r], sp[r], pb);
                phi[dd][r] = fmaf(dta*Ao, Pp*rr, pb);
                A[dd][r]   = An;
                nrm[r]     = fmaf(An, An, nrm[r]);
            }
        }
        /* norm clip across all d (8 wave-partials), double-buffered: one barrier per iter */
        #pragma unroll
        for (int r = 0; r < 4; r++) red[pbuf][w*256 + nn[r]] = nrm[r];
        __syncthreads();
        float scl[4];
        #pragma unroll
        for (int r = 0; r < 4; r++){
            float t = 0.0f;
            #pragma unroll
            for (int wp = 0; wp < 8; wp++) t += red[pbuf][wp*256 + nn[r]];
            scl[r] = (t > 1.0f) ? rsqrtf(t) : 1.0f;
        }
        #pragma unroll
        for (int dd = 0; dd < 4; dd++)
            #pragma unroll
            for (int r = 0; r < 4; r++) A[dd][r] *= scl[r];
    }

    /* ---- readout: Ac[d][c] = relu(sum_n Wcomp[c][n-1] A[n][d] + bcomp[c]); DPP wave-sum ---- */
    #pragma unroll
    for (int dd = 0; dd < 4; dd++) A[dd][0] *= m0;   /* kill n==0 slot */

    for (int c = 0; c < 32; c++){
        float wv[4];
        #pragma unroll
        for (int r = 0; r < 4; r++){
            const int idx = c*255 + nn[r] - 1;
            wv[r] = Wcomp[idx < 0 ? 0 : idx];
        }
        const float bc = bcomp[c];
        #pragma unroll
        for (int dd = 0; dd < 4; dd++){
            float v = wv[0] * A[dd][0];
            v = fmaf(wv[1], A[dd][1], v);
            v = fmaf(wv[2], A[dd][2], v);
            v = fmaf(wv[3], A[dd][3], v);
            v = wave_sum63(v);
            if (l == 63)
                ac[(w*4 + dd)*32 + c] = fmaxf(v + bc, 0.0f);
        }
    }
    __syncthreads();

    /* ro[k] = sum_j Wread[k][j] * ac[j] + bread[k]; k = 0..63, 8 partials each */
    {
        const int k = tid >> 3, part = tid & 7;
        const float4* Wr4 = (const float4*)Wread + k*256;
        const float4* ac4 = (const float4*)ac;
        float s = 0.0f;
        #pragma unroll 4
        for (int jj = 0; jj < 32; jj++){
            const int j4 = part + 8*jj;
            const float4 wv = Wr4[j4];
            const float4 av = ac4[j4];
            s = fmaf(wv.x, av.x, s); s = fmaf(wv.y, av.y, s);
            s = fmaf(wv.z, av.z, s); s = fmaf(wv.w, av.w, s);
        }
        rop[tid] = s;
    }
    __syncthreads();
    if (tid < 32){
        float ra = bread[tid], rp = bread[tid + 32];
        #pragma unroll
        for (int p = 0; p < 8; p++){
            ra += rop[tid*8 + p];
            rp += rop[(tid + 32)*8 + p];
        }
        const float amp = softplus_f(ra);
        const float ph  = PI_F * tanhf(rp * pcpl);
        const float cph = __cosf(ph);
        /* PLANAR output (verified R7): chunk0 = Re(psi), chunk1 = amplitude, chunk2 = phase */
        const int o = b*32 + tid;
        out[o]         = amp * cph;   /* Re(psi) */
        out[Bb*32 + o] = amp;         /* amplitude */
        out[Bb*64 + o] = ph;          /* phase */
    }
}

extern "C" void kernel_launch(void* const* d_in, const int* in_sizes, int n_in,
                              void* d_out, int out_size, void* d_ws, size_t ws_size,
                              hipStream_t stream) {
    const float* ns      = (const float*)d_in[0];   /* [B][512] */
    const float* Ws      = (const float*)d_in[1];   /* [256][512] */
    const float* bs      = (const float*)d_in[2];   /* [256] */
    const float* WA      = (const float*)d_in[3];   /* [32][32] */
    const float* bA      = (const float*)d_in[4];   /* [32] */
    const float* WP      = (const float*)d_in[5];   /* [32][32] */
    const float* bP      = (const float*)d_in[6];   /* [32] */
    const float* psiA0   = (const float*)d_in[7];   /* [255*32] */
    const float* psiP0   = (const float*)d_in[8];   /* [255*32] */
    const float* Wcomp   = (const float*)d_in[9];   /* [32*255] */
    const float* bcomp   = (const float*)d_in[10];  /* [32] */
    const float* Wread   = (const float*)d_in[11];  /* [64*1024] */
    const float* bread   = (const float*)d_in[12];  /* [64] */
    const float* p_alpha = (const float*)d_in[13];
    const float* p_msq   = (const float*)d_in[14];
    const float* p_pw    = (const float*)d_in[15];
    const float* p_iw    = (const float*)d_in[16];
    const float* p_evo   = (const float*)d_in[17];
    const float* p_pcpl  = (const float*)d_in[18];

    const int Bb = in_sizes[0] / 512;               /* 1024 */

    if (ws_size >= (size_t)(512*256*sizeof(float))){
        float* WsT = (float*)d_ws;                  /* [512][256] */
        transpose_ws<<<32, 256, 0, stream>>>(Ws, WsT);
        fused_kernel<true><<<Bb, 512, 0, stream>>>(ns, Ws, WsT, bs, WA, bA, WP, bP,
                                                   psiA0, psiP0, Wcomp, bcomp,
                                                   Wread, bread, p_alpha, p_msq, p_pw, p_iw,
                                                   p_evo, p_pcpl, (float*)d_out, Bb);
    } else {
        fused_kernel<false><<<Bb, 512, 0, stream>>>(ns, Ws, nullptr, bs, WA, bA, WP, bP,
                                                    psiA0, psiP0, Wcomp, bcomp,
                                                    Wread, bread, p_alpha, p_msq, p_pw, p_iw,
                                                    p_evo, p_pcpl, (float*)d_out, Bb);
    }
}

// Round 13
// 332.820 us; speedup vs baseline: 1.0877x; 1.0877x over previous
//
#include <hip/hip_runtime.h>
#include <math.h>

#define PI_F   3.14159265358979f
#define QF     0.88249690258459546f   /* exp(-1/8) */
#define INV255 (1.0f/255.0f)

__device__ __forceinline__ float softplus_f(float x){
    return fmaxf(x, 0.0f) + __logf(1.0f + __expf(-fabsf(x)));
}
__device__ __forceinline__ float tanh_fast(float x){
    const float e = __expf(2.0f*x);
    return fmaf(-2.0f, __builtin_amdgcn_rcpf(e + 1.0f), 1.0f);
}

/* ---- lane exchanges (all HW-verified equivalent R1==R2; row_ror:8 verified R11) ---- */
template<int CTRL>
__device__ __forceinline__ float dppmov(float x){
    return __int_as_float(__builtin_amdgcn_mov_dpp(__float_as_int(x), CTRL, 0xF, 0xF, false));
}
__device__ __forceinline__ float lxor1 (float x){ return dppmov<0xB1>(x);  }  /* quad_perm(1,0,3,2) */
__device__ __forceinline__ float lxor2 (float x){ return dppmov<0x4E>(x);  }  /* quad_perm(2,3,0,1) */
__device__ __forceinline__ float lxor8 (float x){ return dppmov<0x128>(x); }  /* row_ror:8 == i^8   */
__device__ __forceinline__ float lxor4 (float x){ return __int_as_float(__builtin_amdgcn_ds_swizzle(__float_as_int(x), 0x101F)); }
__device__ __forceinline__ float lxor16(float x){ return __int_as_float(__builtin_amdgcn_ds_swizzle(__float_as_int(x), 0x401F)); }
__device__ __forceinline__ float lxor32(float x){ return __shfl_xor(x, 32, 64); }

template<int CTRL>
__device__ __forceinline__ float dppadd(float v){
    return v + __int_as_float(__builtin_amdgcn_update_dpp(0, __float_as_int(v), CTRL, 0xF, 0xF, true));
}
/* full 64-lane sum, result valid in lane 63 (verified R11) */
__device__ __forceinline__ float wave_sum63(float v){
    v = dppadd<0x111>(v);   /* row_shr:1  */
    v = dppadd<0x112>(v);   /* row_shr:2  */
    v = dppadd<0x114>(v);   /* row_shr:4  */
    v = dppadd<0x118>(v);   /* row_shr:8  */
    v = dppadd<0x142>(v);   /* row_bcast:15 */
    v = dppadd<0x143>(v);   /* row_bcast:31 */
    return v;
}

/* Weighted-Hadamard butterfly, bits 0..5 on lanes, 6..7 on regs. Stages commute. */
__device__ __forceinline__ void bfly20(float (&x)[5][4]){
    const float qv = QF;
    #pragma unroll
    for (int a = 0; a < 5; a++){
        #pragma unroll
        for (int r = 0; r < 4; r++) x[a][r] = fmaf(lxor1 (x[a][r]), qv, x[a][r]);
    }
    #pragma unroll
    for (int a = 0; a < 5; a++){
        #pragma unroll
        for (int r = 0; r < 4; r++) x[a][r] = fmaf(lxor2 (x[a][r]), qv, x[a][r]);
    }
    #pragma unroll
    for (int a = 0; a < 5; a++){
        #pragma unroll
        for (int r = 0; r < 4; r++) x[a][r] = fmaf(lxor8 (x[a][r]), qv, x[a][r]);
    }
    #pragma unroll
    for (int a = 0; a < 5; a++){
        #pragma unroll
        for (int r = 0; r < 4; r++) x[a][r] = fmaf(lxor4 (x[a][r]), qv, x[a][r]);
    }
    #pragma unroll
    for (int a = 0; a < 5; a++){
        #pragma unroll
        for (int r = 0; r < 4; r++) x[a][r] = fmaf(lxor16(x[a][r]), qv, x[a][r]);
    }
    #pragma unroll
    for (int a = 0; a < 5; a++){
        #pragma unroll
        for (int r = 0; r < 4; r++) x[a][r] = fmaf(lxor32(x[a][r]), qv, x[a][r]);
    }
    #pragma unroll
    for (int a = 0; a < 5; a++){
        float t0 = x[a][0], t2 = x[a][2];
        x[a][0] = fmaf(QF, x[a][1], x[a][0]);
        x[a][1] = fmaf(QF, t0,      x[a][1]);
        x[a][2] = fmaf(QF, x[a][3], x[a][2]);
        x[a][3] = fmaf(QF, t2,      x[a][3]);
        t0 = x[a][0]; float t1 = x[a][1];
        x[a][0] = fmaf(QF, x[a][2], x[a][0]);
        x[a][1] = fmaf(QF, x[a][3], x[a][1]);
        x[a][2] = fmaf(QF, t0,      x[a][2]);
        x[a][3] = fmaf(QF, t1,      x[a][3]);
    }
}

/* ---- transpose Ws [256][512] -> WsT [512][256] ---- */
__global__ __launch_bounds__(256) void transpose_ws(
        const float* __restrict__ Ws, float* __restrict__ WsT)
{
    __shared__ float tile[64][65];
    const int rt = blockIdx.x & 3, ct = blockIdx.x >> 2;
    const int r0 = rt*64, c0 = ct*64;
    const int tx = threadIdx.x & 63, ty = threadIdx.x >> 6;
    #pragma unroll
    for (int k = 0; k < 16; k++){
        const int row = ty*16 + k;
        tile[row][tx] = Ws[(r0+row)*512 + c0 + tx];
    }
    __syncthreads();
    #pragma unroll
    for (int k = 0; k < 16; k++){
        const int row = ty*16 + k;
        WsT[(c0+row)*256 + r0 + tx] = tile[tx][row];
    }
}

/* ---------------- single fused kernel: one block = one batch element (R11 structure) -------------------------- */
template<bool USET>
__global__ __launch_bounds__(256) void fused_kernel(
        const float* __restrict__ ns,     /* [B][512] */
        const float* __restrict__ Ws,     /* [256][512] */
        const float* __restrict__ WsT,    /* [512][256] or null */
        const float* __restrict__ bs,     /* [256] */
        const float* __restrict__ WA,     /* [32][32] */
        const float* __restrict__ bA,     /* [32] */
        const float* __restrict__ WP,     /* [32][32] */
        const float* __restrict__ bP,     /* [32] */
        const float* __restrict__ psiA0,  /* [255*32] */
        const float* __restrict__ psiP0,  /* [255*32] */
        const float* __restrict__ Wcomp,  /* [32*255] */
        const float* __restrict__ bcomp,  /* [32] */
        const float* __restrict__ Wread,  /* [64*1024] */
        const float* __restrict__ bread,  /* [64] */
        const float* __restrict__ p_alpha, const float* __restrict__ p_msq,
        const float* __restrict__ p_pw,    const float* __restrict__ p_iw,
        const float* __restrict__ p_evo,   const float* __restrict__ p_pcpl,
        float* __restrict__ out, int Bb)
{
    __shared__ __align__(16) float nsb[512];
    __shared__ __align__(16) float fe[256];
    __shared__ __align__(16) float hA[256];
    __shared__ __align__(16) float hP[256];
    __shared__ __align__(16) float red[2][1024];   /* double-buffered norm-clip */
    __shared__ __align__(16) float ac[1024];
    __shared__ __align__(16) float rop[256];

    const int b   = blockIdx.x;
    const int tid = threadIdx.x;
    const int w   = tid >> 6, l = tid & 63;

    const float alpha = p_alpha[0], msq = p_msq[0], pw = p_pw[0], iw = p_iw[0];
    const float pcpl  = p_pcpl[0];
    const float dt    = 1.0f / (1.0f + __expf(-p_evo[0]));
    const float dta  = dt * alpha * INV255;
    const float dtpw = dt * pw * INV255;
    const float c0   = 1.0f - dt * (msq + iw);
    const float dtiw = dt * iw;

    /* ---- front-end: feats[f] = ns[b]·Ws_row(f) + bs[f], f = s*32+d = tid ---- */
    nsb[tid]       = ns[b*512 + tid];
    nsb[tid + 256] = ns[b*512 + 256 + tid];
    __syncthreads();
    if (USET){
        float f = bs[tid];
        const float4* nb4 = (const float4*)nsb;
        #pragma unroll 8
        for (int j4 = 0; j4 < 128; j4++){
            const float4 nv = nb4[j4];
            const float* col = WsT + j4*1024 + tid;
            f = fmaf(col[0],   nv.x, f);
            f = fmaf(col[256], nv.y, f);
            f = fmaf(col[512], nv.z, f);
            f = fmaf(col[768], nv.w, f);
        }
        fe[tid] = f;
    } else {
        float f = bs[tid];
        const float4* wr  = (const float4*)(Ws + tid*512);
        const float4* nb4 = (const float4*)nsb;
        #pragma unroll 8
        for (int i = 0; i < 128; i++){
            const float4 wv = wr[i], nv = nb4[i];
            f = fmaf(wv.x, nv.x, f); f = fmaf(wv.y, nv.y, f);
            f = fmaf(wv.z, nv.z, f); f = fmaf(wv.w, nv.w, f);
        }
        fe[tid] = f;
    }
    __syncthreads();
    {   /* fold through W_A / W_phi (linearity of the member-mean) */
        const int s = tid >> 5, d = tid & 31;
        float a = 0.0f, p = 0.0f;
        #pragma unroll 8
        for (int dp = 0; dp < 32; dp++){
            const float fv = fe[s*32 + dp];
            a = fmaf(WA[d*32 + dp], fv, a);
            p = fmaf(WP[d*32 + dp], fv, p);
        }
        hA[tid] = a; hP[tid] = p;
    }
    __syncthreads();

    /* per-thread clique constants: n = l + 64r */
    int   nn[4];
    float krow[4], rdep[4];
    const float m0 = (l == 0) ? 0.0f : 1.0f;
    float c18;
    { const float t1 = 1.0f + QF, t2 = t1*t1, t4 = t2*t2; c18 = t4*t4; } /* (1+q)^8 */
    #pragma unroll
    for (int r = 0; r < 4; r++){
        nn[r] = l + 64*r;
        const int pop = __popc(nn[r]);
        krow[r]  = c18 - __expf(-0.125f * (float)pop);
        rdep[r]  = 1.0f / (float)(pop ? pop : 1);
    }

    /* state + loop-invariant drive terms (pre-scaled by dt*iw); d = w*8 + dd */
    float A[8][4], phi[8][4], CAp[8][4], Dsp[8][4], Dcp[8][4];

    #pragma unroll
    for (int dd = 0; dd < 8; dd++){
        const int d = w*8 + dd;
        const float bAd = bA[d], bPd = bP[d];
        float gA_[8], gP_[8];
        #pragma unroll
        for (int s = 0; s < 8; s++){ gA_[s] = hA[s*32 + d]; gP_[s] = hP[s*32 + d]; }
        #pragma unroll
        for (int r = 0; r < 4; r++){
            float sA = 0.0f, sP = 0.0f;
            #pragma unroll
            for (int s = 0; s < 8; s++){
                if ((nn[r] >> s) & 1){ sA += gA_[s]; sP += gP_[s]; }
            }
            const float uA  = fmaf(sA, rdep[r], bAd);
            const float uP  = fmaf(sP, rdep[r], bPd);
            const float Ain = softplus_f(uA);
            const float pin = PI_F * tanh_fast(uP);
            const float si = __sinf(pin), ci = __cosf(pin);   /* native v_sin/v_cos */
            const float ca = dtiw * Ain;
            CAp[dd][r] = ca; Dsp[dd][r] = ca * si; Dcp[dd][r] = ca * ci;
            const int nm1 = (nn[r] > 0) ? (nn[r] - 1) : 0;
            A[dd][r]   = softplus_f(psiA0[nm1*32 + d]);
            phi[dd][r] = psiP0[nm1*32 + d];
        }
    }

    for (int it = 0; it < 5; it++){
        const int pbuf = it & 1;
        float nrm[4] = {0.f, 0.f, 0.f, 0.f};
        #pragma unroll
        for (int dd = 0; dd < 8; dd++){
            float sp[4], cp[4];
            float x[5][4];
            {
                sp[0] = __sinf(phi[dd][0]); cp[0] = __cosf(phi[dd][0]);
                const float xa = A[dd][0] * m0;
                x[0][0] = xa;
                x[1][0] = sp[0] * m0;
                x[2][0] = cp[0] * m0;
                x[3][0] = xa * cp[0];
                x[4][0] = xa * sp[0];
            }
            #pragma unroll
            for (int r = 1; r < 4; r++){
                sp[r] = __sinf(phi[dd][r]); cp[r] = __cosf(phi[dd][r]);
                const float xa = A[dd][r];
                x[0][r] = xa;
                x[1][r] = sp[r];
                x[2][r] = cp[r];
                x[3][r] = xa * cp[r];
                x[4][r] = xa * sp[r];
            }
            bfly20(x);
            #pragma unroll
            for (int r = 0; r < 4; r++){
                const float Ao   = A[dd][r];
                const float lapp = fmaf(-krow[r], Ao, x[0][r]);
                const float Vp   = fmaf(cp[r], x[3][r], sp[r]*x[4][r]);
                float Aarg = fmaf(c0, Ao, CAp[dd][r]);
                Aarg = fmaf(dta,  lapp, Aarg);
                Aarg = fmaf(dtpw, Vp,   Aarg);
                const float An = softplus_f(Aarg);
                const float Pp = fmaf(-sp[r], x[2][r], cp[r]*x[1][r]);
                const float rr = __builtin_amdgcn_rcpf(An + 1e-8f);
                float pb = fmaf(Dsp[dd][r], cp[r], phi[dd][r]);
                pb = fmaf(-Dcp[dd][r], sp[r], pb);
                phi[dd][r] = fmaf(dta*Ao, Pp*rr, pb);
                A[dd][r]   = An;
                nrm[r]     = fmaf(An, An, nrm[r]);
            }
        }
        /* norm clip across all d (cross-wave), double-buffered: one barrier per iter */
        #pragma unroll
        for (int r = 0; r < 4; r++) red[pbuf][w*256 + nn[r]] = nrm[r];
        __syncthreads();
        float scl[4];
        #pragma unroll
        for (int r = 0; r < 4; r++){
            const float t = red[pbuf][nn[r]] + red[pbuf][256 + nn[r]]
                          + red[pbuf][512 + nn[r]] + red[pbuf][768 + nn[r]];
            scl[r] = (t > 1.0f) ? rsqrtf(t) : 1.0f;
        }
        #pragma unroll
        for (int dd = 0; dd < 8; dd++)
            #pragma unroll
            for (int r = 0; r < 4; r++) A[dd][r] *= scl[r];
    }

    /* ---- readout: Ac[d][c] = relu(sum_n Wcomp[c][n-1] A[n][d] + bcomp[c]); DPP wave-sum ---- */
    #pragma unroll
    for (int dd = 0; dd < 8; dd++) A[dd][0] *= m0;   /* kill n==0 slot */

    for (int c = 0; c < 32; c++){
        float wv[4];
        #pragma unroll
        for (int r = 0; r < 4; r++){
            const int idx = c*255 + nn[r] - 1;
            wv[r] = Wcomp[idx < 0 ? 0 : idx];
        }
        const float bc = bcomp[c];
        #pragma unroll
        for (int dd = 0; dd < 8; dd++){
            float v = wv[0] * A[dd][0];
            v = fmaf(wv[1], A[dd][1], v);
            v = fmaf(wv[2], A[dd][2], v);
            v = fmaf(wv[3], A[dd][3], v);
            v = wave_sum63(v);
            if (l == 63)
                ac[(w*8 + dd)*32 + c] = fmaxf(v + bc, 0.0f);
        }
    }
    __syncthreads();

    /* ro[k] = sum_j Wread[k][j] * ac[j] + bread[k]; k = 0..63 split over 4 partials */
    {
        const int k = tid >> 2, part = tid & 3;
        const float4* Wr4 = (const float4*)Wread + k*256;
        const float4* ac4 = (const float4*)ac;
        float s = 0.0f;
        #pragma unroll 4
        for (int jj = 0; jj < 64; jj++){
            const int j4 = part + 4*jj;
            const float4 wv = Wr4[j4];
            const float4 av = ac4[j4];
            s = fmaf(wv.x, av.x, s); s = fmaf(wv.y, av.y, s);
            s = fmaf(wv.z, av.z, s); s = fmaf(wv.w, av.w, s);
        }
        rop[tid] = s;
    }
    __syncthreads();
    if (tid < 32){
        const float ra = rop[tid*4] + rop[tid*4+1] + rop[tid*4+2] + rop[tid*4+3] + bread[tid];
        const int   t2 = tid + 32;
        const float rp = rop[t2*4] + rop[t2*4+1] + rop[t2*4+2] + rop[t2*4+3] + bread[t2];
        const float amp = softplus_f(ra);
        const float ph  = PI_F * tanhf(rp * pcpl);
        const float cph = __cosf(ph);
        /* PLANAR output (verified R7): chunk0 = Re(psi), chunk1 = amplitude, chunk2 = phase */
        const int o = b*32 + tid;
        out[o]         = amp * cph;   /* Re(psi) */
        out[Bb*32 + o] = amp;         /* amplitude */
        out[Bb*64 + o] = ph;          /* phase */
    }
}

extern "C" void kernel_launch(void* const* d_in, const int* in_sizes, int n_in,
                              void* d_out, int out_size, void* d_ws, size_t ws_size,
                              hipStream_t stream) {
    const float* ns      = (const float*)d_in[0];   /* [B][512] */
    const float* Ws      = (const float*)d_in[1];   /* [256][512] */
    const float* bs      = (const float*)d_in[2];   /* [256] */
    const float* WA      = (const float*)d_in[3];   /* [32][32] */
    const float* bA      = (const float*)d_in[4];   /* [32] */
    const float* WP      = (const float*)d_in[5];   /* [32][32] */
    const float* bP      = (const float*)d_in[6];   /* [32] */
    const float* psiA0   = (const float*)d_in[7];   /* [255*32] */
    const float* psiP0   = (const float*)d_in[8];   /* [255*32] */
    const float* Wcomp   = (const float*)d_in[9];   /* [32*255] */
    const float* bcomp   = (const float*)d_in[10];  /* [32] */
    const float* Wread   = (const float*)d_in[11];  /* [64*1024] */
    const float* bread   = (const float*)d_in[12];  /* [64] */
    const float* p_alpha = (const float*)d_in[13];
    const float* p_msq   = (const float*)d_in[14];
    const float* p_pw    = (const float*)d_in[15];
    const float* p_iw    = (const float*)d_in[16];
    const float* p_evo   = (const float*)d_in[17];
    const float* p_pcpl  = (const float*)d_in[18];

    const int Bb = in_sizes[0] / 512;               /* 1024 */

    if (ws_size >= (size_t)(512*256*sizeof(float))){
        float* WsT = (float*)d_ws;                  /* [512][256] */
        transpose_ws<<<32, 256, 0, stream>>>(Ws, WsT);
        fused_kernel<true><<<Bb, 256, 0, stream>>>(ns, Ws, WsT, bs, WA, bA, WP, bP,
                                                   psiA0, psiP0, Wcomp, bcomp,
                                                   Wread, bread, p_alpha, p_msq, p_pw, p_iw,
                                                   p_evo, p_pcpl, (float*)d_out, Bb);
    } else {
        fused_kernel<false><<<Bb, 256, 0, stream>>>(ns, Ws, nullptr, bs, WA, bA, WP, bP,
                                                    psiA0, psiP0, Wcomp, bcomp,
                                                    Wread, bread, p_alpha, p_msq, p_pw, p_iw,
                                                    p_evo, p_pcpl, (float*)d_out, Bb);
    }
}

// Round 14
// 321.331 us; speedup vs baseline: 1.1266x; 1.0358x over previous
//
#include <hip/hip_runtime.h>
#include <math.h>

#define PI_F   3.14159265358979f
#define QF     0.88249690258459546f   /* exp(-1/8) */
#define INV255 (1.0f/255.0f)

__device__ __forceinline__ float softplus_f(float x){
    return fmaxf(x, 0.0f) + __logf(1.0f + __expf(-fabsf(x)));
}
__device__ __forceinline__ float tanh_fast(float x){
    const float e = __expf(2.0f*x);
    return fmaf(-2.0f, __builtin_amdgcn_rcpf(e + 1.0f), 1.0f);
}

/* ---- lane exchanges (all HW-verified equivalent R1==R2; row_ror:8 verified R11) ---- */
template<int CTRL>
__device__ __forceinline__ float dppmov(float x){
    return __int_as_float(__builtin_amdgcn_mov_dpp(__float_as_int(x), CTRL, 0xF, 0xF, false));
}
__device__ __forceinline__ float lxor1 (float x){ return dppmov<0xB1>(x);  }  /* quad_perm(1,0,3,2) */
__device__ __forceinline__ float lxor2 (float x){ return dppmov<0x4E>(x);  }  /* quad_perm(2,3,0,1) */
__device__ __forceinline__ float lxor8 (float x){ return dppmov<0x128>(x); }  /* row_ror:8 == i^8   */
__device__ __forceinline__ float lxor4 (float x){ return __int_as_float(__builtin_amdgcn_ds_swizzle(__float_as_int(x), 0x101F)); }
__device__ __forceinline__ float lxor16(float x){ return __int_as_float(__builtin_amdgcn_ds_swizzle(__float_as_int(x), 0x401F)); }
__device__ __forceinline__ float lxor32(float x){ return __shfl_xor(x, 32, 64); }

template<int CTRL>
__device__ __forceinline__ float dppadd(float v){
    return v + __int_as_float(__builtin_amdgcn_update_dpp(0, __float_as_int(v), CTRL, 0xF, 0xF, true));
}
/* full 64-lane sum, result valid in lane 63 (verified R11) */
__device__ __forceinline__ float wave_sum63(float v){
    v = dppadd<0x111>(v);   /* row_shr:1  */
    v = dppadd<0x112>(v);   /* row_shr:2  */
    v = dppadd<0x114>(v);   /* row_shr:4  */
    v = dppadd<0x118>(v);   /* row_shr:8  */
    v = dppadd<0x142>(v);   /* row_bcast:15 */
    v = dppadd<0x143>(v);   /* row_bcast:31 */
    return v;
}

/* Weighted-Hadamard butterfly, bits 0..5 on lanes, 6..7 on regs. Stages commute. */
template<int NA>
__device__ __forceinline__ void bflyN(float (&x)[NA][4]){
    const float qv = QF;
    #pragma unroll
    for (int a = 0; a < NA; a++){
        #pragma unroll
        for (int r = 0; r < 4; r++) x[a][r] = fmaf(lxor1 (x[a][r]), qv, x[a][r]);
    }
    #pragma unroll
    for (int a = 0; a < NA; a++){
        #pragma unroll
        for (int r = 0; r < 4; r++) x[a][r] = fmaf(lxor2 (x[a][r]), qv, x[a][r]);
    }
    #pragma unroll
    for (int a = 0; a < NA; a++){
        #pragma unroll
        for (int r = 0; r < 4; r++) x[a][r] = fmaf(lxor8 (x[a][r]), qv, x[a][r]);
    }
    #pragma unroll
    for (int a = 0; a < NA; a++){
        #pragma unroll
        for (int r = 0; r < 4; r++) x[a][r] = fmaf(lxor4 (x[a][r]), qv, x[a][r]);
    }
    #pragma unroll
    for (int a = 0; a < NA; a++){
        #pragma unroll
        for (int r = 0; r < 4; r++) x[a][r] = fmaf(lxor16(x[a][r]), qv, x[a][r]);
    }
    #pragma unroll
    for (int a = 0; a < NA; a++){
        #pragma unroll
        for (int r = 0; r < 4; r++) x[a][r] = fmaf(lxor32(x[a][r]), qv, x[a][r]);
    }
    #pragma unroll
    for (int a = 0; a < NA; a++){
        float t0 = x[a][0], t2 = x[a][2];
        x[a][0] = fmaf(QF, x[a][1], x[a][0]);
        x[a][1] = fmaf(QF, t0,      x[a][1]);
        x[a][2] = fmaf(QF, x[a][3], x[a][2]);
        x[a][3] = fmaf(QF, t2,      x[a][3]);
        t0 = x[a][0]; float t1 = x[a][1];
        x[a][0] = fmaf(QF, x[a][2], x[a][0]);
        x[a][1] = fmaf(QF, x[a][3], x[a][1]);
        x[a][2] = fmaf(QF, t0,      x[a][2]);
        x[a][3] = fmaf(QF, t1,      x[a][3]);
    }
}

/* ---- prep kernel: blocks 0..31 transpose Ws -> WsT[512][256];
       blocks 32..63 transpose psiA0/psiP0 -> [32][256] d-major (col 0 zeroed) ---- */
__global__ __launch_bounds__(256) void prep_kernel(
        const float* __restrict__ Ws,    const float* __restrict__ psiA0,
        const float* __restrict__ psiP0, float* __restrict__ WsT,
        float* __restrict__ psiA0T,      float* __restrict__ psiP0T)
{
    if (blockIdx.x < 32){
        __shared__ float tile[64][65];
        const int rt = blockIdx.x & 3, ct = blockIdx.x >> 2;
        const int r0 = rt*64, c0 = ct*64;
        const int tx = threadIdx.x & 63, ty = threadIdx.x >> 6;
        #pragma unroll
        for (int k = 0; k < 16; k++){
            const int row = ty*16 + k;
            tile[row][tx] = Ws[(r0+row)*512 + c0 + tx];
        }
        __syncthreads();
        #pragma unroll
        for (int k = 0; k < 16; k++){
            const int row = ty*16 + k;
            WsT[(c0+row)*256 + r0 + tx] = tile[tx][row];
        }
    } else {
        const int d = blockIdx.x - 32;       /* 0..31 */
        const int n = threadIdx.x;           /* 0..255 */
        const float a = (n > 0) ? psiA0[(n-1)*32 + d] : 0.0f;
        const float p = (n > 0) ? psiP0[(n-1)*32 + d] : 0.0f;
        psiA0T[d*256 + n] = a;
        psiP0T[d*256 + n] = p;
    }
}

/* ---------------- single fused kernel: one block = one batch element (R11 structure + iter-5 peel) ------------ */
template<bool USET>
__global__ __launch_bounds__(256) void fused_kernel(
        const float* __restrict__ ns,     /* [B][512] */
        const float* __restrict__ Ws,     /* [256][512] */
        const float* __restrict__ WsT,    /* [512][256] or null */
        const float* __restrict__ bs,     /* [256] */
        const float* __restrict__ WA,     /* [32][32] */
        const float* __restrict__ bA,     /* [32] */
        const float* __restrict__ WP,     /* [32][32] */
        const float* __restrict__ bP,     /* [32] */
        const float* __restrict__ psiA0,  /* [255*32] */
        const float* __restrict__ psiP0,  /* [255*32] */
        const float* __restrict__ psiA0T, /* [32][256] or null */
        const float* __restrict__ psiP0T, /* [32][256] or null */
        const float* __restrict__ Wcomp,  /* [32*255] */
        const float* __restrict__ bcomp,  /* [32] */
        const float* __restrict__ Wread,  /* [64*1024] */
        const float* __restrict__ bread,  /* [64] */
        const float* __restrict__ p_alpha, const float* __restrict__ p_msq,
        const float* __restrict__ p_pw,    const float* __restrict__ p_iw,
        const float* __restrict__ p_evo,   const float* __restrict__ p_pcpl,
        float* __restrict__ out, int Bb)
{
    __shared__ __align__(16) float nsb[512];
    __shared__ __align__(16) float fe[256];
    __shared__ __align__(16) float hA[256];
    __shared__ __align__(16) float hP[256];
    __shared__ __align__(16) float red[2][1024];
    __shared__ __align__(16) float ac[1024];
    __shared__ __align__(16) float rop[256];

    const int b   = blockIdx.x;
    const int tid = threadIdx.x;
    const int w   = tid >> 6, l = tid & 63;

    const float alpha = p_alpha[0], msq = p_msq[0], pw = p_pw[0], iw = p_iw[0];
    const float pcpl  = p_pcpl[0];
    const float dt    = 1.0f / (1.0f + __expf(-p_evo[0]));
    const float dta  = dt * alpha * INV255;
    const float dtpw = dt * pw * INV255;
    const float c0   = 1.0f - dt * (msq + iw);
    const float dtiw = dt * iw;

    /* ---- front-end: feats[f] = ns[b]·Ws_row(f) + bs[f], f = s*32+d = tid ---- */
    nsb[tid]       = ns[b*512 + tid];
    nsb[tid + 256] = ns[b*512 + 256 + tid];
    __syncthreads();
    if (USET){
        float f = bs[tid];
        const float4* nb4 = (const float4*)nsb;
        #pragma unroll 8
        for (int j4 = 0; j4 < 128; j4++){
            const float4 nv = nb4[j4];
            const float* col = WsT + j4*1024 + tid;
            f = fmaf(col[0],   nv.x, f);
            f = fmaf(col[256], nv.y, f);
            f = fmaf(col[512], nv.z, f);
            f = fmaf(col[768], nv.w, f);
        }
        fe[tid] = f;
    } else {
        float f = bs[tid];
        const float4* wr  = (const float4*)(Ws + tid*512);
        const float4* nb4 = (const float4*)nsb;
        #pragma unroll 8
        for (int i = 0; i < 128; i++){
            const float4 wv = wr[i], nv = nb4[i];
            f = fmaf(wv.x, nv.x, f); f = fmaf(wv.y, nv.y, f);
            f = fmaf(wv.z, nv.z, f); f = fmaf(wv.w, nv.w, f);
        }
        fe[tid] = f;
    }
    __syncthreads();
    {   /* fold through W_A / W_phi (linearity of the member-mean) */
        const int s = tid >> 5, d = tid & 31;
        float a = 0.0f, p = 0.0f;
        #pragma unroll 8
        for (int dp = 0; dp < 32; dp++){
            const float fv = fe[s*32 + dp];
            a = fmaf(WA[d*32 + dp], fv, a);
            p = fmaf(WP[d*32 + dp], fv, p);
        }
        hA[tid] = a; hP[tid] = p;
    }
    __syncthreads();

    /* per-thread clique constants: n = l + 64r */
    int   nn[4];
    float krow[4], rdep[4];
    const float m0 = (l == 0) ? 0.0f : 1.0f;
    float c18;
    { const float t1 = 1.0f + QF, t2 = t1*t1, t4 = t2*t2; c18 = t4*t4; } /* (1+q)^8 */
    #pragma unroll
    for (int r = 0; r < 4; r++){
        nn[r] = l + 64*r;
        const int pop = __popc(nn[r]);
        krow[r]  = c18 - __expf(-0.125f * (float)pop);
        rdep[r]  = 1.0f / (float)(pop ? pop : 1);
    }

    /* state + loop-invariant drive terms (pre-scaled by dt*iw); d = w*8 + dd */
    float A[8][4], phi[8][4], CAp[8][4], Dsp[8][4], Dcp[8][4];

    #pragma unroll
    for (int dd = 0; dd < 8; dd++){
        const int d = w*8 + dd;
        const float bAd = bA[d], bPd = bP[d];
        float gA_[8], gP_[8];
        #pragma unroll
        for (int s = 0; s < 8; s++){ gA_[s] = hA[s*32 + d]; gP_[s] = hP[s*32 + d]; }
        #pragma unroll
        for (int r = 0; r < 4; r++){
            float sA = 0.0f, sP = 0.0f;
            #pragma unroll
            for (int s = 0; s < 8; s++){
                if ((nn[r] >> s) & 1){ sA += gA_[s]; sP += gP_[s]; }
            }
            const float uA  = fmaf(sA, rdep[r], bAd);
            const float uP  = fmaf(sP, rdep[r], bPd);
            const float Ain = softplus_f(uA);
            const float pin = PI_F * tanh_fast(uP);
            const float si = __sinf(pin), ci = __cosf(pin);
            const float ca = dtiw * Ain;
            CAp[dd][r] = ca; Dsp[dd][r] = ca * si; Dcp[dd][r] = ca * ci;
            if (USET){
                A[dd][r]   = softplus_f(psiA0T[d*256 + nn[r]]);   /* coalesced */
                phi[dd][r] = psiP0T[d*256 + nn[r]];
            } else {
                const int nm1 = (nn[r] > 0) ? (nn[r] - 1) : 0;
                A[dd][r]   = softplus_f(psiA0[nm1*32 + d]);
                phi[dd][r] = psiP0[nm1*32 + d];
            }
        }
    }

    /* ---- iterations 0..3: full dynamics ---- */
    for (int it = 0; it < 4; it++){
        const int pbuf = it & 1;
        float nrm[4] = {0.f, 0.f, 0.f, 0.f};
        #pragma unroll
        for (int dd = 0; dd < 8; dd++){
            float sp[4], cp[4];
            float x[5][4];
            {
                sp[0] = __sinf(phi[dd][0]); cp[0] = __cosf(phi[dd][0]);
                const float xa = A[dd][0] * m0;
                x[0][0] = xa;
                x[1][0] = sp[0] * m0;
                x[2][0] = cp[0] * m0;
                x[3][0] = xa * cp[0];
                x[4][0] = xa * sp[0];
            }
            #pragma unroll
            for (int r = 1; r < 4; r++){
                sp[r] = __sinf(phi[dd][r]); cp[r] = __cosf(phi[dd][r]);
                const float xa = A[dd][r];
                x[0][r] = xa;
                x[1][r] = sp[r];
                x[2][r] = cp[r];
                x[3][r] = xa * cp[r];
                x[4][r] = xa * sp[r];
            }
            bflyN<5>(x);
            #pragma unroll
            for (int r = 0; r < 4; r++){
                const float Ao   = A[dd][r];
                const float lapp = fmaf(-krow[r], Ao, x[0][r]);
                const float Vp   = fmaf(cp[r], x[3][r], sp[r]*x[4][r]);
                float Aarg = fmaf(c0, Ao, CAp[dd][r]);
                Aarg = fmaf(dta,  lapp, Aarg);
                Aarg = fmaf(dtpw, Vp,   Aarg);
                const float An = softplus_f(Aarg);
                const float Pp = fmaf(-sp[r], x[2][r], cp[r]*x[1][r]);
                const float rr = __builtin_amdgcn_rcpf(An + 1e-8f);
                float pb = fmaf(Dsp[dd][r], cp[r], phi[dd][r]);
                pb = fmaf(-Dcp[dd][r], sp[r], pb);
                phi[dd][r] = fmaf(dta*Ao, Pp*rr, pb);
                A[dd][r]   = An;
                nrm[r]     = fmaf(An, An, nrm[r]);
            }
        }
        #pragma unroll
        for (int r = 0; r < 4; r++) red[pbuf][w*256 + nn[r]] = nrm[r];
        __syncthreads();
        float scl[4];
        #pragma unroll
        for (int r = 0; r < 4; r++){
            const float t = red[pbuf][nn[r]] + red[pbuf][256 + nn[r]]
                          + red[pbuf][512 + nn[r]] + red[pbuf][768 + nn[r]];
            scl[r] = (t > 1.0f) ? rsqrtf(t) : 1.0f;
        }
        #pragma unroll
        for (int dd = 0; dd < 8; dd++)
            #pragma unroll
            for (int r = 0; r < 4; r++) A[dd][r] *= scl[r];
    }

    /* ---- iteration 4 (peeled): phi-update is dead code -> 3-array butterfly, A-only epilogue ---- */
    {
        float nrm[4] = {0.f, 0.f, 0.f, 0.f};
        #pragma unroll
        for (int dd = 0; dd < 8; dd++){
            float sp[4], cp[4];
            float y[3][4];
            {
                sp[0] = __sinf(phi[dd][0]); cp[0] = __cosf(phi[dd][0]);
                const float xa = A[dd][0] * m0;
                y[0][0] = xa;
                y[1][0] = xa * cp[0];
                y[2][0] = xa * sp[0];
            }
            #pragma unroll
            for (int r = 1; r < 4; r++){
                sp[r] = __sinf(phi[dd][r]); cp[r] = __cosf(phi[dd][r]);
                const float xa = A[dd][r];
                y[0][r] = xa;
                y[1][r] = xa * cp[r];
                y[2][r] = xa * sp[r];
            }
            bflyN<3>(y);
            #pragma unroll
            for (int r = 0; r < 4; r++){
                const float Ao   = A[dd][r];
                const float lapp = fmaf(-krow[r], Ao, y[0][r]);
                const float Vp   = fmaf(cp[r], y[1][r], sp[r]*y[2][r]);
                float Aarg = fmaf(c0, Ao, CAp[dd][r]);
                Aarg = fmaf(dta,  lapp, Aarg);
                Aarg = fmaf(dtpw, Vp,   Aarg);
                const float An = softplus_f(Aarg);
                A[dd][r]   = An;
                nrm[r]     = fmaf(An, An, nrm[r]);
            }
        }
        #pragma unroll
        for (int r = 0; r < 4; r++) red[0][w*256 + nn[r]] = nrm[r];
        __syncthreads();
        float scl[4];
        #pragma unroll
        for (int r = 0; r < 4; r++){
            const float t = red[0][nn[r]] + red[0][256 + nn[r]]
                          + red[0][512 + nn[r]] + red[0][768 + nn[r]];
            scl[r] = (t > 1.0f) ? rsqrtf(t) : 1.0f;
        }
        #pragma unroll
        for (int dd = 0; dd < 8; dd++)
            #pragma unroll
            for (int r = 0; r < 4; r++) A[dd][r] *= scl[r];
    }

    /* ---- readout: Ac[d][c] = relu(sum_n Wcomp[c][n-1] A[n][d] + bcomp[c]); DPP wave-sum ---- */
    #pragma unroll
    for (int dd = 0; dd < 8; dd++) A[dd][0] *= m0;   /* kill n==0 slot */

    for (int c = 0; c < 32; c++){
        float wv[4];
        #pragma unroll
        for (int r = 0; r < 4; r++){
            const int idx = c*255 + nn[r] - 1;
            wv[r] = Wcomp[idx < 0 ? 0 : idx];
        }
        const float bc = bcomp[c];
        #pragma unroll
        for (int dd = 0; dd < 8; dd++){
            float v = wv[0] * A[dd][0];
            v = fmaf(wv[1], A[dd][1], v);
            v = fmaf(wv[2], A[dd][2], v);
            v = fmaf(wv[3], A[dd][3], v);
            v = wave_sum63(v);
            if (l == 63)
                ac[(w*8 + dd)*32 + c] = fmaxf(v + bc, 0.0f);
        }
    }
    __syncthreads();

    /* ro[k] = sum_j Wread[k][j] * ac[j] + bread[k]; k = 0..63 split over 4 partials */
    {
        const int k = tid >> 2, part = tid & 3;
        const float4* Wr4 = (const float4*)Wread + k*256;
        const float4* ac4 = (const float4*)ac;
        float s = 0.0f;
        #pragma unroll 4
        for (int jj = 0; jj < 64; jj++){
            const int j4 = part + 4*jj;
            const float4 wv = Wr4[j4];
            const float4 av = ac4[j4];
            s = fmaf(wv.x, av.x, s); s = fmaf(wv.y, av.y, s);
            s = fmaf(wv.z, av.z, s); s = fmaf(wv.w, av.w, s);
        }
        rop[tid] = s;
    }
    __syncthreads();
    if (tid < 32){
        const float ra = rop[tid*4] + rop[tid*4+1] + rop[tid*4+2] + rop[tid*4+3] + bread[tid];
        const int   t2 = tid + 32;
        const float rp = rop[t2*4] + rop[t2*4+1] + rop[t2*4+2] + rop[t2*4+3] + bread[t2];
        const float amp = softplus_f(ra);
        const float ph  = PI_F * tanhf(rp * pcpl);
        const float cph = __cosf(ph);
        /* PLANAR output (verified R7): chunk0 = Re(psi), chunk1 = amplitude, chunk2 = phase */
        const int o = b*32 + tid;
        out[o]         = amp * cph;   /* Re(psi) */
        out[Bb*32 + o] = amp;         /* amplitude */
        out[Bb*64 + o] = ph;          /* phase */
    }
}

extern "C" void kernel_launch(void* const* d_in, const int* in_sizes, int n_in,
                              void* d_out, int out_size, void* d_ws, size_t ws_size,
                              hipStream_t stream) {
    const float* ns      = (const float*)d_in[0];   /* [B][512] */
    const float* Ws      = (const float*)d_in[1];   /* [256][512] */
    const float* bs      = (const float*)d_in[2];   /* [256] */
    const float* WA      = (const float*)d_in[3];   /* [32][32] */
    const float* bA      = (const float*)d_in[4];   /* [32] */
    const float* WP      = (const float*)d_in[5];   /* [32][32] */
    const float* bP      = (const float*)d_in[6];   /* [32] */
    const float* psiA0   = (const float*)d_in[7];   /* [255*32] */
    const float* psiP0   = (const float*)d_in[8];   /* [255*32] */
    const float* Wcomp   = (const float*)d_in[9];   /* [32*255] */
    const float* bcomp   = (const float*)d_in[10];  /* [32] */
    const float* Wread   = (const float*)d_in[11];  /* [64*1024] */
    const float* bread   = (const float*)d_in[12];  /* [64] */
    const float* p_alpha = (const float*)d_in[13];
    const float* p_msq   = (const float*)d_in[14];
    const float* p_pw    = (const float*)d_in[15];
    const float* p_iw    = (const float*)d_in[16];
    const float* p_evo   = (const float*)d_in[17];
    const float* p_pcpl  = (const float*)d_in[18];

    const int Bb = in_sizes[0] / 512;               /* 1024 */

    const size_t need = (size_t)(512*256 + 2*32*256) * sizeof(float);
    if (ws_size >= need){
        float* WsT    = (float*)d_ws;               /* [512][256] */
        float* psiA0T = WsT + 512*256;              /* [32][256]  */
        float* psiP0T = psiA0T + 32*256;            /* [32][256]  */
        prep_kernel<<<64, 256, 0, stream>>>(Ws, psiA0, psiP0, WsT, psiA0T, psiP0T);
        fused_kernel<true><<<Bb, 256, 0, stream>>>(ns, Ws, WsT, bs, WA, bA, WP, bP,
                                                   psiA0, psiP0, psiA0T, psiP0T,
                                                   Wcomp, bcomp, Wread, bread,
                                                   p_alpha, p_msq, p_pw, p_iw,
                                                   p_evo, p_pcpl, (float*)d_out, Bb);
    } else {
        fused_kernel<false><<<Bb, 256, 0, stream>>>(ns, Ws, nullptr, bs, WA, bA, WP, bP,
                                                    psiA0, psiP0, nullptr, nullptr,
                                                    Wcomp, bcomp, Wread, bread,
                                                    p_alpha, p_msq, p_pw, p_iw,
                                                    p_evo, p_pcpl, (float*)d_out, Bb);
    }
}

// Round 15
// 309.580 us; speedup vs baseline: 1.1693x; 1.0380x over previous
//
#include <hip/hip_runtime.h>
#include <math.h>

#define PI_F   3.14159265358979f
#define QF     0.88249690258459546f   /* exp(-1/8) */
#define INV255 (1.0f/255.0f)

__device__ __forceinline__ float softplus_f(float x){
    return fmaxf(x, 0.0f) + __logf(1.0f + __expf(-fabsf(x)));
}
__device__ __forceinline__ float tanh_fast(float x){
    const float e = __expf(2.0f*x);
    return fmaf(-2.0f, __builtin_amdgcn_rcpf(e + 1.0f), 1.0f);
}

/* ---- lane exchanges (all HW-verified equivalent R1==R2; row_ror:8 verified R11) ---- */
template<int CTRL>
__device__ __forceinline__ float dppmov(float x){
    return __int_as_float(__builtin_amdgcn_mov_dpp(__float_as_int(x), CTRL, 0xF, 0xF, false));
}
__device__ __forceinline__ float lxor1 (float x){ return dppmov<0xB1>(x);  }  /* quad_perm(1,0,3,2) */
__device__ __forceinline__ float lxor2 (float x){ return dppmov<0x4E>(x);  }  /* quad_perm(2,3,0,1) */
__device__ __forceinline__ float lxor8 (float x){ return dppmov<0x128>(x); }  /* row_ror:8 == i^8   */
__device__ __forceinline__ float lxor4 (float x){ return __int_as_float(__builtin_amdgcn_ds_swizzle(__float_as_int(x), 0x101F)); }
__device__ __forceinline__ float lxor16(float x){ return __int_as_float(__builtin_amdgcn_ds_swizzle(__float_as_int(x), 0x401F)); }
__device__ __forceinline__ float lxor32(float x){ return __shfl_xor(x, 32, 64); }

template<int CTRL>
__device__ __forceinline__ float dppadd(float v){
    return v + __int_as_float(__builtin_amdgcn_update_dpp(0, __float_as_int(v), CTRL, 0xF, 0xF, true));
}
/* full 64-lane sum, result valid in lane 63 (verified R11) */
__device__ __forceinline__ float wave_sum63(float v){
    v = dppadd<0x111>(v);   /* row_shr:1  */
    v = dppadd<0x112>(v);   /* row_shr:2  */
    v = dppadd<0x114>(v);   /* row_shr:4  */
    v = dppadd<0x118>(v);   /* row_shr:8  */
    v = dppadd<0x142>(v);   /* row_bcast:15 */
    v = dppadd<0x143>(v);   /* row_bcast:31 */
    return v;
}

/* Weighted-Hadamard butterfly, bits 0..5 on lanes, 6..7 on regs. Stages commute. */
template<int NA>
__device__ __forceinline__ void bflyN(float (&x)[NA][4]){
    const float qv = QF;
    #pragma unroll
    for (int a = 0; a < NA; a++){
        #pragma unroll
        for (int r = 0; r < 4; r++) x[a][r] = fmaf(lxor1 (x[a][r]), qv, x[a][r]);
    }
    #pragma unroll
    for (int a = 0; a < NA; a++){
        #pragma unroll
        for (int r = 0; r < 4; r++) x[a][r] = fmaf(lxor2 (x[a][r]), qv, x[a][r]);
    }
    #pragma unroll
    for (int a = 0; a < NA; a++){
        #pragma unroll
        for (int r = 0; r < 4; r++) x[a][r] = fmaf(lxor8 (x[a][r]), qv, x[a][r]);
    }
    #pragma unroll
    for (int a = 0; a < NA; a++){
        #pragma unroll
        for (int r = 0; r < 4; r++) x[a][r] = fmaf(lxor4 (x[a][r]), qv, x[a][r]);
    }
    #pragma unroll
    for (int a = 0; a < NA; a++){
        #pragma unroll
        for (int r = 0; r < 4; r++) x[a][r] = fmaf(lxor16(x[a][r]), qv, x[a][r]);
    }
    #pragma unroll
    for (int a = 0; a < NA; a++){
        #pragma unroll
        for (int r = 0; r < 4; r++) x[a][r] = fmaf(lxor32(x[a][r]), qv, x[a][r]);
    }
    #pragma unroll
    for (int a = 0; a < NA; a++){
        float t0 = x[a][0], t2 = x[a][2];
        x[a][0] = fmaf(QF, x[a][1], x[a][0]);
        x[a][1] = fmaf(QF, t0,      x[a][1]);
        x[a][2] = fmaf(QF, x[a][3], x[a][2]);
        x[a][3] = fmaf(QF, t2,      x[a][3]);
        t0 = x[a][0]; float t1 = x[a][1];
        x[a][0] = fmaf(QF, x[a][2], x[a][0]);
        x[a][1] = fmaf(QF, x[a][3], x[a][1]);
        x[a][2] = fmaf(QF, t0,      x[a][2]);
        x[a][3] = fmaf(QF, t1,      x[a][3]);
    }
}

/* ---- prep: blocks 0..31 transpose Ws -> WsT[512][256];
       block 32: iteration-0 peel constants X,P0,sp0,cp0,phi0 [32][256] (batch-independent) ---- */
__global__ __launch_bounds__(256) void prep_kernel(
        const float* __restrict__ Ws,    const float* __restrict__ psiA0,
        const float* __restrict__ psiP0, const float* __restrict__ p_alpha,
        const float* __restrict__ p_msq, const float* __restrict__ p_pw,
        const float* __restrict__ p_iw,  const float* __restrict__ p_evo,
        float* __restrict__ WsT,  float* __restrict__ Xc,  float* __restrict__ P0c,
        float* __restrict__ S0c,  float* __restrict__ C0c, float* __restrict__ F0c)
{
    if (blockIdx.x < 32){
        __shared__ float tile[64][65];
        const int rt = blockIdx.x & 3, ct = blockIdx.x >> 2;
        const int r0 = rt*64, c0t = ct*64;
        const int tx = threadIdx.x & 63, ty = threadIdx.x >> 6;
        #pragma unroll
        for (int k = 0; k < 16; k++){
            const int row = ty*16 + k;
            tile[row][tx] = Ws[(r0+row)*512 + c0t + tx];
        }
        __syncthreads();
        #pragma unroll
        for (int k = 0; k < 16; k++){
            const int row = ty*16 + k;
            WsT[(c0t+row)*256 + r0 + tx] = tile[tx][row];
        }
        return;
    }
    /* block 32: batch-independent iteration-0 dynamics */
    const int tid = threadIdx.x;
    const int w = tid >> 6, l = tid & 63;
    const float alpha = p_alpha[0], msq = p_msq[0], pw = p_pw[0], iw = p_iw[0];
    const float dt   = 1.0f / (1.0f + __expf(-p_evo[0]));
    const float dta  = dt * alpha * INV255;
    const float dtpw = dt * pw * INV255;
    const float c0   = 1.0f - dt * (msq + iw);
    const float m0 = (l == 0) ? 0.0f : 1.0f;
    int nn[4]; float krow[4];
    float c18;
    { const float t1 = 1.0f + QF, t2 = t1*t1, t4 = t2*t2; c18 = t4*t4; }
    #pragma unroll
    for (int r = 0; r < 4; r++){
        nn[r] = l + 64*r;
        krow[r] = c18 - __expf(-0.125f * (float)__popc(nn[r]));
    }
    #pragma unroll
    for (int dd = 0; dd < 8; dd++){
        const int d = w*8 + dd;
        float A0[4], ph0[4], sp[4], cp[4];
        float x[5][4];
        #pragma unroll
        for (int r = 0; r < 4; r++){
            const int n = nn[r];
            A0[r]  = (n > 0) ? softplus_f(psiA0[(n-1)*32 + d]) : 0.0f;
            ph0[r] = (n > 0) ? psiP0[(n-1)*32 + d] : 0.0f;
            sp[r] = __sinf(ph0[r]); cp[r] = __cosf(ph0[r]);
            const float mk = (r == 0) ? m0 : 1.0f;
            const float xa = A0[r] * mk;
            x[0][r] = xa;
            x[1][r] = sp[r] * mk;
            x[2][r] = cp[r] * mk;
            x[3][r] = xa * cp[r];
            x[4][r] = xa * sp[r];
        }
        bflyN<5>(x);
        #pragma unroll
        for (int r = 0; r < 4; r++){
            const float Ao   = A0[r];
            const float lapp = fmaf(-krow[r], Ao, x[0][r]);
            const float Vp   = fmaf(cp[r], x[3][r], sp[r]*x[4][r]);
            const float Pp   = fmaf(-sp[r], x[2][r], cp[r]*x[1][r]);
            float X = c0 * Ao;
            X = fmaf(dta,  lapp, X);
            X = fmaf(dtpw, Vp,   X);
            const int idx = d*256 + nn[r];
            Xc[idx]  = X;
            P0c[idx] = dta * Ao * Pp;
            S0c[idx] = sp[r];
            C0c[idx] = cp[r];
            F0c[idx] = ph0[r];
        }
    }
}

/* ---------------- fused kernel: one block = one batch element; peel-0 + 3 full iters + peel-4 ------------------ */
template<bool USET>
__global__ __launch_bounds__(256) void fused_kernel(
        const float* __restrict__ ns,     /* [B][512] */
        const float* __restrict__ Ws,     /* [256][512] */
        const float* __restrict__ WsT,    /* [512][256] or null */
        const float* __restrict__ bs,     /* [256] */
        const float* __restrict__ WA,     /* [32][32] */
        const float* __restrict__ bA,     /* [32] */
        const float* __restrict__ WP,     /* [32][32] */
        const float* __restrict__ bP,     /* [32] */
        const float* __restrict__ psiA0,  /* [255*32] */
        const float* __restrict__ psiP0,  /* [255*32] */
        const float* __restrict__ Xc,     /* [32][256] or null */
        const float* __restrict__ P0c,    /* [32][256] or null */
        const float* __restrict__ S0c,    /* [32][256] or null */
        const float* __restrict__ C0c,    /* [32][256] or null */
        const float* __restrict__ F0c,    /* [32][256] or null */
        const float* __restrict__ Wcomp,  /* [32*255] */
        const float* __restrict__ bcomp,  /* [32] */
        const float* __restrict__ Wread,  /* [64*1024] */
        const float* __restrict__ bread,  /* [64] */
        const float* __restrict__ p_alpha, const float* __restrict__ p_msq,
        const float* __restrict__ p_pw,    const float* __restrict__ p_iw,
        const float* __restrict__ p_evo,   const float* __restrict__ p_pcpl,
        float* __restrict__ out, int Bb)
{
    __shared__ __align__(16) float nsb[512];
    __shared__ __align__(16) float fe[256];
    __shared__ __align__(16) float hA[256];
    __shared__ __align__(16) float hP[256];
    __shared__ __align__(16) float red[2][1024];
    __shared__ __align__(16) float ac[1024];
    __shared__ __align__(16) float rop[256];

    const int b   = blockIdx.x;
    const int tid = threadIdx.x;
    const int w   = tid >> 6, l = tid & 63;

    const float alpha = p_alpha[0], msq = p_msq[0], pw = p_pw[0], iw = p_iw[0];
    const float pcpl  = p_pcpl[0];
    const float dt    = 1.0f / (1.0f + __expf(-p_evo[0]));
    const float dta  = dt * alpha * INV255;
    const float dtpw = dt * pw * INV255;
    const float c0   = 1.0f - dt * (msq + iw);
    const float dtiw = dt * iw;

    /* ---- front-end: feats[f] = ns[b]·Ws_row(f) + bs[f], f = s*32+d = tid ---- */
    nsb[tid]       = ns[b*512 + tid];
    nsb[tid + 256] = ns[b*512 + 256 + tid];
    __syncthreads();
    if (USET){
        float f = bs[tid];
        const float4* nb4 = (const float4*)nsb;
        #pragma unroll 8
        for (int j4 = 0; j4 < 128; j4++){
            const float4 nv = nb4[j4];
            const float* col = WsT + j4*1024 + tid;
            f = fmaf(col[0],   nv.x, f);
            f = fmaf(col[256], nv.y, f);
            f = fmaf(col[512], nv.z, f);
            f = fmaf(col[768], nv.w, f);
        }
        fe[tid] = f;
    } else {
        float f = bs[tid];
        const float4* wr  = (const float4*)(Ws + tid*512);
        const float4* nb4 = (const float4*)nsb;
        #pragma unroll 8
        for (int i = 0; i < 128; i++){
            const float4 wv = wr[i], nv = nb4[i];
            f = fmaf(wv.x, nv.x, f); f = fmaf(wv.y, nv.y, f);
            f = fmaf(wv.z, nv.z, f); f = fmaf(wv.w, nv.w, f);
        }
        fe[tid] = f;
    }
    __syncthreads();
    {   /* fold through W_A / W_phi (linearity of the member-mean) */
        const int s = tid >> 5, d = tid & 31;
        float a = 0.0f, p = 0.0f;
        #pragma unroll 8
        for (int dp = 0; dp < 32; dp++){
            const float fv = fe[s*32 + dp];
            a = fmaf(WA[d*32 + dp], fv, a);
            p = fmaf(WP[d*32 + dp], fv, p);
        }
        hA[tid] = a; hP[tid] = p;
    }
    __syncthreads();

    /* per-thread clique constants: n = l + 64r */
    int   nn[4];
    float krow[4], rdep[4];
    const float m0 = (l == 0) ? 0.0f : 1.0f;
    float c18;
    { const float t1 = 1.0f + QF, t2 = t1*t1, t4 = t2*t2; c18 = t4*t4; }
    #pragma unroll
    for (int r = 0; r < 4; r++){
        nn[r] = l + 64*r;
        const int pop = __popc(nn[r]);
        krow[r]  = c18 - __expf(-0.125f * (float)pop);
        rdep[r]  = 1.0f / (float)(pop ? pop : 1);
    }

    /* state + drive terms + ITERATION-0 PEEL (batch-dep part only); d = w*8 + dd */
    float A[8][4], phi[8][4], CAp[8][4], Dsp[8][4], Dcp[8][4];
    float nrm0[4] = {0.f, 0.f, 0.f, 0.f};

    #pragma unroll
    for (int dd = 0; dd < 8; dd++){
        const int d = w*8 + dd;
        const float bAd = bA[d], bPd = bP[d];
        float gA_[8], gP_[8];
        #pragma unroll
        for (int s = 0; s < 8; s++){ gA_[s] = hA[s*32 + d]; gP_[s] = hP[s*32 + d]; }
        #pragma unroll
        for (int r = 0; r < 4; r++){
            float sA = 0.0f, sP = 0.0f;
            #pragma unroll
            for (int s = 0; s < 8; s++){
                if ((nn[r] >> s) & 1){ sA += gA_[s]; sP += gP_[s]; }
            }
            const float uA  = fmaf(sA, rdep[r], bAd);
            const float uP  = fmaf(sP, rdep[r], bPd);
            const float Ain = softplus_f(uA);
            const float pin = PI_F * tanh_fast(uP);
            const float si = __sinf(pin), ci = __cosf(pin);
            const float ca = dtiw * Ain;
            CAp[dd][r] = ca; Dsp[dd][r] = ca * si; Dcp[dd][r] = ca * ci;
            if (USET){
                /* iter-0 peel: A1 = softplus(X + CAp); phi1 from precomputed constants */
                const int idx = d*256 + nn[r];
                const float An = softplus_f(Xc[idx] + ca);
                const float rr = __builtin_amdgcn_rcpf(An + 1e-8f);
                float pb = fmaf(Dsp[dd][r], C0c[idx], F0c[idx]);
                pb = fmaf(-Dcp[dd][r], S0c[idx], pb);
                phi[dd][r] = fmaf(P0c[idx], rr, pb);
                A[dd][r]   = An;
                nrm0[r]    = fmaf(An, An, nrm0[r]);
            } else {
                const int nm1 = (nn[r] > 0) ? (nn[r] - 1) : 0;
                A[dd][r]   = softplus_f(psiA0[nm1*32 + d]);
                phi[dd][r] = psiP0[nm1*32 + d];
            }
        }
    }

    if (USET){
        /* norm-clip for peeled iteration 0 (buffer 0) */
        #pragma unroll
        for (int r = 0; r < 4; r++) red[0][w*256 + nn[r]] = nrm0[r];
        __syncthreads();
        float scl[4];
        #pragma unroll
        for (int r = 0; r < 4; r++){
            const float t = red[0][nn[r]] + red[0][256 + nn[r]]
                          + red[0][512 + nn[r]] + red[0][768 + nn[r]];
            scl[r] = (t > 1.0f) ? rsqrtf(t) : 1.0f;
        }
        #pragma unroll
        for (int dd = 0; dd < 8; dd++)
            #pragma unroll
            for (int r = 0; r < 4; r++) A[dd][r] *= scl[r];
    }

    /* ---- full iterations (3 when peeled, 4 otherwise) ---- */
    const int NFULL = USET ? 3 : 4;
    for (int it = 0; it < NFULL; it++){
        const int pbuf = USET ? ((it + 1) & 1) : (it & 1);
        float nrm[4] = {0.f, 0.f, 0.f, 0.f};
        #pragma unroll
        for (int dd = 0; dd < 8; dd++){
            float sp[4], cp[4];
            float x[5][4];
            {
                sp[0] = __sinf(phi[dd][0]); cp[0] = __cosf(phi[dd][0]);
                const float xa = A[dd][0] * m0;
                x[0][0] = xa;
                x[1][0] = sp[0] * m0;
                x[2][0] = cp[0] * m0;
                x[3][0] = xa * cp[0];
                x[4][0] = xa * sp[0];
            }
            #pragma unroll
            for (int r = 1; r < 4; r++){
                sp[r] = __sinf(phi[dd][r]); cp[r] = __cosf(phi[dd][r]);
                const float xa = A[dd][r];
                x[0][r] = xa;
                x[1][r] = sp[r];
                x[2][r] = cp[r];
                x[3][r] = xa * cp[r];
                x[4][r] = xa * sp[r];
            }
            bflyN<5>(x);
            #pragma unroll
            for (int r = 0; r < 4; r++){
                const float Ao   = A[dd][r];
                const float lapp = fmaf(-krow[r], Ao, x[0][r]);
                const float Vp   = fmaf(cp[r], x[3][r], sp[r]*x[4][r]);
                float Aarg = fmaf(c0, Ao, CAp[dd][r]);
                Aarg = fmaf(dta,  lapp, Aarg);
                Aarg = fmaf(dtpw, Vp,   Aarg);
                const float An = softplus_f(Aarg);
                const float Pp = fmaf(-sp[r], x[2][r], cp[r]*x[1][r]);
                const float rr = __builtin_amdgcn_rcpf(An + 1e-8f);
                float pb = fmaf(Dsp[dd][r], cp[r], phi[dd][r]);
                pb = fmaf(-Dcp[dd][r], sp[r], pb);
                phi[dd][r] = fmaf(dta*Ao, Pp*rr, pb);
                A[dd][r]   = An;
                nrm[r]     = fmaf(An, An, nrm[r]);
            }
        }
        #pragma unroll
        for (int r = 0; r < 4; r++) red[pbuf][w*256 + nn[r]] = nrm[r];
        __syncthreads();
        float scl[4];
        #pragma unroll
        for (int r = 0; r < 4; r++){
            const float t = red[pbuf][nn[r]] + red[pbuf][256 + nn[r]]
                          + red[pbuf][512 + nn[r]] + red[pbuf][768 + nn[r]];
            scl[r] = (t > 1.0f) ? rsqrtf(t) : 1.0f;
        }
        #pragma unroll
        for (int dd = 0; dd < 8; dd++)
            #pragma unroll
            for (int r = 0; r < 4; r++) A[dd][r] *= scl[r];
    }

    /* ---- final iteration (peeled): phi-update dead -> 3-array butterfly, A-only epilogue ---- */
    {
        float nrm[4] = {0.f, 0.f, 0.f, 0.f};
        #pragma unroll
        for (int dd = 0; dd < 8; dd++){
            float sp[4], cp[4];
            float y[3][4];
            {
                sp[0] = __sinf(phi[dd][0]); cp[0] = __cosf(phi[dd][0]);
                const float xa = A[dd][0] * m0;
                y[0][0] = xa;
                y[1][0] = xa * cp[0];
                y[2][0] = xa * sp[0];
            }
            #pragma unroll
            for (int r = 1; r < 4; r++){
                sp[r] = __sinf(phi[dd][r]); cp[r] = __cosf(phi[dd][r]);
                const float xa = A[dd][r];
                y[0][r] = xa;
                y[1][r] = xa * cp[r];
                y[2][r] = xa * sp[r];
            }
            bflyN<3>(y);
            #pragma unroll
            for (int r = 0; r < 4; r++){
                const float Ao   = A[dd][r];
                const float lapp = fmaf(-krow[r], Ao, y[0][r]);
                const float Vp   = fmaf(cp[r], y[1][r], sp[r]*y[2][r]);
                float Aarg = fmaf(c0, Ao, CAp[dd][r]);
                Aarg = fmaf(dta,  lapp, Aarg);
                Aarg = fmaf(dtpw, Vp,   Aarg);
                const float An = softplus_f(Aarg);
                A[dd][r]   = An;
                nrm[r]     = fmaf(An, An, nrm[r]);
            }
        }
        #pragma unroll
        for (int r = 0; r < 4; r++) red[0][w*256 + nn[r]] = nrm[r];
        __syncthreads();
        float scl[4];
        #pragma unroll
        for (int r = 0; r < 4; r++){
            const float t = red[0][nn[r]] + red[0][256 + nn[r]]
                          + red[0][512 + nn[r]] + red[0][768 + nn[r]];
            scl[r] = (t > 1.0f) ? rsqrtf(t) : 1.0f;
        }
        #pragma unroll
        for (int dd = 0; dd < 8; dd++)
            #pragma unroll
            for (int r = 0; r < 4; r++) A[dd][r] *= scl[r];
    }

    /* ---- readout: Ac[d][c] = relu(sum_n Wcomp[c][n-1] A[n][d] + bcomp[c]); DPP wave-sum ---- */
    #pragma unroll
    for (int dd = 0; dd < 8; dd++) A[dd][0] *= m0;   /* kill n==0 slot */

    for (int c = 0; c < 32; c++){
        float wv[4];
        #pragma unroll
        for (int r = 0; r < 4; r++){
            const int idx = c*255 + nn[r] - 1;
            wv[r] = Wcomp[idx < 0 ? 0 : idx];
        }
        const float bc = bcomp[c];
        #pragma unroll
        for (int dd = 0; dd < 8; dd++){
            float v = wv[0] * A[dd][0];
            v = fmaf(wv[1], A[dd][1], v);
            v = fmaf(wv[2], A[dd][2], v);
            v = fmaf(wv[3], A[dd][3], v);
            v = wave_sum63(v);
            if (l == 63)
                ac[(w*8 + dd)*32 + c] = fmaxf(v + bc, 0.0f);
        }
    }
    __syncthreads();

    /* ro[k] = sum_j Wread[k][j] * ac[j] + bread[k]; k = 0..63 split over 4 partials */
    {
        const int k = tid >> 2, part = tid & 3;
        const float4* Wr4 = (const float4*)Wread + k*256;
        const float4* ac4 = (const float4*)ac;
        float s = 0.0f;
        #pragma unroll 4
        for (int jj = 0; jj < 64; jj++){
            const int j4 = part + 4*jj;
            const float4 wv = Wr4[j4];
            const float4 av = ac4[j4];
            s = fmaf(wv.x, av.x, s); s = fmaf(wv.y, av.y, s);
            s = fmaf(wv.z, av.z, s); s = fmaf(wv.w, av.w, s);
        }
        rop[tid] = s;
    }
    __syncthreads();
    if (tid < 32){
        const float ra = rop[tid*4] + rop[tid*4+1] + rop[tid*4+2] + rop[tid*4+3] + bread[tid];
        const int   t2 = tid + 32;
        const float rp = rop[t2*4] + rop[t2*4+1] + rop[t2*4+2] + rop[t2*4+3] + bread[t2];
        const float amp = softplus_f(ra);
        const float ph  = PI_F * tanhf(rp * pcpl);
        const float cph = __cosf(ph);
        /* PLANAR output (verified R7): chunk0 = Re(psi), chunk1 = amplitude, chunk2 = phase */
        const int o = b*32 + tid;
        out[o]         = amp * cph;   /* Re(psi) */
        out[Bb*32 + o] = amp;         /* amplitude */
        out[Bb*64 + o] = ph;          /* phase */
    }
}

extern "C" void kernel_launch(void* const* d_in, const int* in_sizes, int n_in,
                              void* d_out, int out_size, void* d_ws, size_t ws_size,
                              hipStream_t stream) {
    const float* ns      = (const float*)d_in[0];   /* [B][512] */
    const float* Ws      = (const float*)d_in[1];   /* [256][512] */
    const float* bs      = (const float*)d_in[2];   /* [256] */
    const float* WA      = (const float*)d_in[3];   /* [32][32] */
    const float* bA      = (const float*)d_in[4];   /* [32] */
    const float* WP      = (const float*)d_in[5];   /* [32][32] */
    const float* bP      = (const float*)d_in[6];   /* [32] */
    const float* psiA0   = (const float*)d_in[7];   /* [255*32] */
    const float* psiP0   = (const float*)d_in[8];   /* [255*32] */
    const float* Wcomp   = (const float*)d_in[9];   /* [32*255] */
    const float* bcomp   = (const float*)d_in[10];  /* [32] */
    const float* Wread   = (const float*)d_in[11];  /* [64*1024] */
    const float* bread   = (const float*)d_in[12];  /* [64] */
    const float* p_alpha = (const float*)d_in[13];
    const float* p_msq   = (const float*)d_in[14];
    const float* p_pw    = (const float*)d_in[15];
    const float* p_iw    = (const float*)d_in[16];
    const float* p_evo   = (const float*)d_in[17];
    const float* p_pcpl  = (const float*)d_in[18];

    const int Bb = in_sizes[0] / 512;               /* 1024 */

    const size_t need = (size_t)(512*256 + 5*32*256) * sizeof(float);
    if (ws_size >= need){
        float* WsT = (float*)d_ws;                  /* [512][256] */
        float* Xc  = WsT + 512*256;                 /* [32][256] each */
        float* P0c = Xc  + 32*256;
        float* S0c = P0c + 32*256;
        float* C0c = S0c + 32*256;
        float* F0c = C0c + 32*256;
        prep_kernel<<<33, 256, 0, stream>>>(Ws, psiA0, psiP0,
                                            p_alpha, p_msq, p_pw, p_iw, p_evo,
                                            WsT, Xc, P0c, S0c, C0c, F0c);
        fused_kernel<true><<<Bb, 256, 0, stream>>>(ns, Ws, WsT, bs, WA, bA, WP, bP,
                                                   psiA0, psiP0, Xc, P0c, S0c, C0c, F0c,
                                                   Wcomp, bcomp, Wread, bread,
                                                   p_alpha, p_msq, p_pw, p_iw,
                                                   p_evo, p_pcpl, (float*)d_out, Bb);
    } else {
        fused_kernel<false><<<Bb, 256, 0, stream>>>(ns, Ws, nullptr, bs, WA, bA, WP, bP,
                                                    psiA0, psiP0,
                                                    nullptr, nullptr, nullptr, nullptr, nullptr,
                                                    Wcomp, bcomp, Wread, bread,
                                                    p_alpha, p_msq, p_pw, p_iw,
                                                    p_evo, p_pcpl, (float*)d_out, Bb);
    }
}